// Round 1
// baseline (1571.374 us; speedup 1.0000x reference)
//
#include <hip/hip_runtime.h>

// Problem: x (32,64,128,128) fp32, W (128,64,3,3) fp32
// out = min_{co} conv2d(x, W, SAME)[b, co, h, w] * 2.0 -> (32,1,128,128)
//
// Baseline strategy (round 1): direct conv, one thread per output pixel.
// Register-block 16 output channels so each x load feeds 16 FMAs; W reads are
// wave-uniform (same co/ci for all lanes) -> expect scalar s_load path.
// Fuses the channel-min + scale; conv tensor never materialized.

#define CI 64
#define CO 128
#define HH 128
#define WW 128
#define COT 16   // output channels per accumulator block

__global__ __launch_bounds__(256) void conv_min_kernel(
    const float* __restrict__ x,
    const float* __restrict__ Wt,
    float* __restrict__ out)
{
    const int b  = blockIdx.y;
    const int h0 = blockIdx.x * 2;           // 2 rows per 256-thread block
    const int tx = threadIdx.x & 127;        // w coordinate (coalesced)
    const int ty = threadIdx.x >> 7;         // which of the 2 rows
    const int h  = h0 + ty;
    const int w  = tx;

    const bool r0 = (h - 1) >= 0;
    const bool r2 = (h + 1) < HH;
    const bool c0 = (w - 1) >= 0;
    const bool c2 = (w + 1) < WW;

    const float* xb = x + (size_t)b * CI * HH * WW;

    float vmin = 3.4e38f;

    for (int cb = 0; cb < CO; cb += COT) {
        float acc[COT];
        #pragma unroll
        for (int u = 0; u < COT; ++u) acc[u] = 0.0f;

        #pragma unroll 1
        for (int ci = 0; ci < CI; ++ci) {
            const float* xp = xb + ((size_t)ci * HH + h) * WW + w;

            // 3x3 input patch with zero padding (masked loads; no OOB deref)
            float xv[9];
            xv[0] = (r0 && c0) ? xp[-WW - 1] : 0.0f;
            xv[1] =  r0        ? xp[-WW    ] : 0.0f;
            xv[2] = (r0 && c2) ? xp[-WW + 1] : 0.0f;
            xv[3] =        c0  ? xp[-1     ] : 0.0f;
            xv[4] =              xp[0      ];
            xv[5] =        c2  ? xp[1      ] : 0.0f;
            xv[6] = (r2 && c0) ? xp[ WW - 1] : 0.0f;
            xv[7] =  r2        ? xp[ WW    ] : 0.0f;
            xv[8] = (r2 && c2) ? xp[ WW + 1] : 0.0f;

            #pragma unroll
            for (int u = 0; u < COT; ++u) {
                // wave-uniform address -> scalar load path expected
                const float* wp = Wt + ((size_t)(cb + u) * CI + ci) * 9;
                float s0 = wp[0] * xv[0] + wp[1] * xv[1] + wp[2] * xv[2];
                float s1 = wp[3] * xv[3] + wp[4] * xv[4] + wp[5] * xv[5];
                float s2 = wp[6] * xv[6] + wp[7] * xv[7] + wp[8] * xv[8];
                acc[u] += s0 + s1 + s2;
            }
        }

        #pragma unroll
        for (int u = 0; u < COT; ++u) vmin = fminf(vmin, acc[u]);
    }

    out[((size_t)b * HH + h) * WW + w] = vmin * 2.0f;
}

extern "C" void kernel_launch(void* const* d_in, const int* in_sizes, int n_in,
                              void* d_out, int out_size, void* d_ws, size_t ws_size,
                              hipStream_t stream) {
    const float* x  = (const float*)d_in[0];   // (32,64,128,128)
    const float* Wt = (const float*)d_in[1];   // (128,64,3,3)
    float* out = (float*)d_out;                // (32,1,128,128)

    dim3 grid(HH / 2, 32);   // 64 row-pairs x 32 batches = 2048 blocks
    conv_min_kernel<<<grid, 256, 0, stream>>>(x, Wt, out);
}

// Round 2
// 374.751 us; speedup vs baseline: 4.1931x; 4.1931x over previous
//
#include <hip/hip_runtime.h>

// out = min_co( conv2d(x, W, SAME) ) * 2
// x (32,64,128,128) fp32, W (128,64,3,3) fp32 -> out (32,1,128,128) fp32
//
// Round 2: bf16 MFMA implicit GEMM.
//  prep_x: x -> padded bf16 x_t[b][130][130][64ci], 16B ci-slots swizzled by w&7
//  prep_w: W -> bf16 W_t[tap][co][ci]
//  conv_mfma: per (b,h): GEMM M=128 pixels x N=128 co, K = 9 taps * 64 ci.
//    A staged once via global_load_lds (contiguous 49.9KB), B read from global
//    (144KB total, L2-resident). One barrier. Fused min+scale epilogue.

typedef __attribute__((ext_vector_type(8))) short  short8;   // 8 x bf16
typedef __attribute__((ext_vector_type(8))) unsigned short ushort8;
typedef __attribute__((ext_vector_type(4))) float  float4v;

#define CI 64
#define CO 128
#define HH 128
#define WW 128
#define HP 130
#define WP 130

#define XT_BYTES   ((size_t)32 * HP * WP * CI * 2)   // 69,222,400
#define WT_BYTES   ((size_t)9 * CO * CI * 2)         // 147,456

__device__ __forceinline__ unsigned short f2bf(float f) {
    unsigned int u = __float_as_uint(f);
    u = (u + 0x7fffu + ((u >> 16) & 1u)) >> 16;   // RNE
    return (unsigned short)u;
}

// ---------------- prep kernels ----------------

__global__ __launch_bounds__(256) void prep_x(
    const float* __restrict__ x, unsigned short* __restrict__ xt)
{
    int idx = blockIdx.x * 256 + threadIdx.x;          // (b, hp, wp)
    if (idx >= 32 * HP * WP) return;
    int wp = idx % WP;
    int t  = idx / WP;
    int hp = t % HP;
    int b  = t / HP;
    int h = hp - 1, w = wp - 1;
    unsigned short* outp = xt + (size_t)idx * CI;      // 128 B per pixel
    if (h < 0 || h >= HH || w < 0 || w >= WW) {
        ushort8 z = {0,0,0,0,0,0,0,0};
        #pragma unroll
        for (int s = 0; s < 8; ++s) *(ushort8*)(outp + s * 8) = z;
        return;
    }
    int key = wp & 7;
    const float* xp = x + (((size_t)b * CI) * HH + h) * WW + w;
    #pragma unroll
    for (int s = 0; s < 8; ++s) {
        ushort8 v;
        #pragma unroll
        for (int j = 0; j < 8; ++j)
            v[j] = f2bf(xp[(size_t)(s * 8 + j) * HH * WW]);
        *(ushort8*)(outp + (size_t)(s ^ key) * 8) = v;  // swizzled 16B slot
    }
}

__global__ __launch_bounds__(256) void prep_w(
    const float* __restrict__ Wsrc, unsigned short* __restrict__ wt)
{
    int idx = blockIdx.x * 256 + threadIdx.x;          // (tap, co, ci)
    if (idx >= 9 * CO * CI) return;
    int ci  = idx & 63;
    int t   = idx >> 6;
    int co  = t & 127;
    int tap = t >> 7;
    wt[idx] = f2bf(Wsrc[((size_t)co * CI + ci) * 9 + tap]);
}

// ---------------- main MFMA kernel ----------------

#define LDSA_BYTES (3 * WP * CI * 2)   // 49920

__global__ __launch_bounds__(256, 3) void conv_mfma(
    const unsigned short* __restrict__ xt,
    const unsigned short* __restrict__ wt,
    float* __restrict__ out)
{
    __shared__ char  ldsA[LDSA_BYTES];
    __shared__ float scratch[2][128];

    const int h    = blockIdx.x;       // output row
    const int b    = blockIdx.y;
    const int tid  = threadIdx.x;
    const int wid  = tid >> 6;
    const int lane = tid & 63;
    const int l15  = lane & 15;
    const int quad = lane >> 4;
    const int wm   = wid & 1;          // wave's M half (64 px)
    const int wn   = wid >> 1;         // wave's N half (64 co)
    const int m0   = wm * 64;
    const int n0   = wn * 64;

    // ---- stage A: padded rows h, h+1, h+2 = contiguous 49920 B ----
    const char* src = (const char*)xt + (((size_t)b * HP + h) * WP) * (CI * 2);
    {
        int wbase0 = (tid & 0xC0) * 16;          // wave-uniform
        int loff   = (lane) * 16;
        #pragma unroll
        for (int r = 0; r < 12; ++r) {
            int wbase = r * 4096 + wbase0;
            __builtin_amdgcn_global_load_lds(
                (const __attribute__((address_space(1))) void*)(src + wbase + loff),
                (__attribute__((address_space(3))) void*)(ldsA + wbase),
                16, 0, 0);
        }
        if (wid == 0 && lane < 48) {             // 768 B tail
            int wbase = 12 * 4096;
            __builtin_amdgcn_global_load_lds(
                (const __attribute__((address_space(1))) void*)(src + wbase + loff),
                (__attribute__((address_space(3))) void*)(ldsA + wbase),
                16, 0, 0);
        }
    }
    __syncthreads();

    float4v acc[4][4];
    #pragma unroll
    for (int mt = 0; mt < 4; ++mt)
        #pragma unroll
        for (int nt = 0; nt < 4; ++nt)
            acc[mt][nt] = (float4v){0.f, 0.f, 0.f, 0.f};

    #pragma unroll 1
    for (int tap = 0; tap < 9; ++tap) {
        const int dh = tap / 3;   // = kh
        const int dw = tap % 3;   // = kw
        const int key = (dw + l15) & 7;
        const int pxbase = dh * WP + dw + m0 + l15;
        #pragma unroll
        for (int kc = 0; kc < 2; ++kc) {
            short8 bf[4];
            #pragma unroll
            for (int nt = 0; nt < 4; ++nt) {
                int co = n0 + nt * 16 + l15;
                bf[nt] = *(const short8*)(wt +
                          (((size_t)tap * CO + co) * CI + kc * 32 + quad * 8));
            }
            const int sp = ((kc * 4 + quad) ^ key) * 16;
            short8 af[4];
            #pragma unroll
            for (int mt = 0; mt < 4; ++mt) {
                int px = pxbase + mt * 16;
                af[mt] = *(const short8*)(ldsA + px * 128 + sp);
            }
            #pragma unroll
            for (int mt = 0; mt < 4; ++mt)
                #pragma unroll
                for (int nt = 0; nt < 4; ++nt)
                    acc[mt][nt] = __builtin_amdgcn_mfma_f32_16x16x32_bf16(
                        af[mt], bf[nt], acc[mt][nt], 0, 0, 0);
        }
    }

    // ---- epilogue: min over co, *2 ----
    // lane holds D[m = m0 + mt*16 + quad*4 + reg][n = n0 + nt*16 + l15]
    float pm[4][4];   // [mt][reg] : min over this lane's 4 n-tiles
    #pragma unroll
    for (int mt = 0; mt < 4; ++mt)
        #pragma unroll
        for (int reg = 0; reg < 4; ++reg) {
            float v = acc[mt][0][reg];
            v = fminf(v, acc[mt][1][reg]);
            v = fminf(v, acc[mt][2][reg]);
            v = fminf(v, acc[mt][3][reg]);
            pm[mt][reg] = v;
        }
    // butterfly min over the 16 n-lanes (l15) of each quad
    #pragma unroll
    for (int mask = 1; mask <= 8; mask <<= 1)
        #pragma unroll
        for (int mt = 0; mt < 4; ++mt)
            #pragma unroll
            for (int reg = 0; reg < 4; ++reg)
                pm[mt][reg] = fminf(pm[mt][reg],
                                    __shfl_xor(pm[mt][reg], mask, 64));
    if (l15 == 0) {
        #pragma unroll
        for (int mt = 0; mt < 4; ++mt)
            #pragma unroll
            for (int reg = 0; reg < 4; ++reg)
                scratch[wn][m0 + mt * 16 + quad * 4 + reg] = pm[mt][reg];
    }
    __syncthreads();
    if (tid < 128) {
        float v = fminf(scratch[0][tid], scratch[1][tid]) * 2.0f;
        out[((size_t)b * HH + h) * WW + tid] = v;
    }
}

// ---------------- fallback (round-1 direct conv) ----------------

#define COT 16
__global__ __launch_bounds__(256) void conv_min_fallback(
    const float* __restrict__ x, const float* __restrict__ Wt,
    float* __restrict__ out)
{
    const int b  = blockIdx.y;
    const int h  = blockIdx.x * 2 + (threadIdx.x >> 7);
    const int w  = threadIdx.x & 127;
    const bool r0 = h > 0, r2 = h < HH - 1, c0 = w > 0, c2 = w < WW - 1;
    const float* xb = x + (size_t)b * CI * HH * WW;
    float vmin = 3.4e38f;
    for (int cb = 0; cb < CO; cb += COT) {
        float acc[COT];
        #pragma unroll
        for (int u = 0; u < COT; ++u) acc[u] = 0.0f;
        #pragma unroll 1
        for (int ci = 0; ci < CI; ++ci) {
            const float* xp = xb + ((size_t)ci * HH + h) * WW + w;
            float xv[9];
            xv[0] = (r0 && c0) ? xp[-WW - 1] : 0.0f;
            xv[1] =  r0        ? xp[-WW    ] : 0.0f;
            xv[2] = (r0 && c2) ? xp[-WW + 1] : 0.0f;
            xv[3] =        c0  ? xp[-1     ] : 0.0f;
            xv[4] =              xp[0      ];
            xv[5] =        c2  ? xp[1      ] : 0.0f;
            xv[6] = (r2 && c0) ? xp[ WW - 1] : 0.0f;
            xv[7] =  r2        ? xp[ WW    ] : 0.0f;
            xv[8] = (r2 && c2) ? xp[ WW + 1] : 0.0f;
            #pragma unroll
            for (int u = 0; u < COT; ++u) {
                const float* wp = Wt + ((size_t)(cb + u) * CI + ci) * 9;
                acc[u] += wp[0]*xv[0] + wp[1]*xv[1] + wp[2]*xv[2]
                        + wp[3]*xv[3] + wp[4]*xv[4] + wp[5]*xv[5]
                        + wp[6]*xv[6] + wp[7]*xv[7] + wp[8]*xv[8];
            }
        }
        #pragma unroll
        for (int u = 0; u < COT; ++u) vmin = fminf(vmin, acc[u]);
    }
    out[((size_t)b * HH + h) * WW + w] = vmin * 2.0f;
}

// ---------------- launch ----------------

extern "C" void kernel_launch(void* const* d_in, const int* in_sizes, int n_in,
                              void* d_out, int out_size, void* d_ws, size_t ws_size,
                              hipStream_t stream) {
    const float* x  = (const float*)d_in[0];   // (32,64,128,128)
    const float* Ws = (const float*)d_in[1];   // (128,64,3,3)
    float* out = (float*)d_out;                // (32,1,128,128)

    if (ws_size < XT_BYTES + WT_BYTES) {
        dim3 grid(HH / 2, 32);
        conv_min_fallback<<<grid, 256, 0, stream>>>(x, Ws, out);
        return;
    }

    unsigned short* xt = (unsigned short*)d_ws;
    unsigned short* wt = (unsigned short*)((char*)d_ws + XT_BYTES);

    prep_x<<<(32 * HP * WP + 255) / 256, 256, 0, stream>>>(x, xt);
    prep_w<<<(9 * CO * CI + 255) / 256, 256, 0, stream>>>(Ws, wt);
    conv_mfma<<<dim3(HH, 32), 256, 0, stream>>>(xt, wt, out);
}

// Round 3
// 312.828 us; speedup vs baseline: 5.0231x; 1.1979x over previous
//
#include <hip/hip_runtime.h>

// out = min_co( conv2d(x, W, SAME) ) * 2
// x (32,64,128,128) fp32, W (128,64,3,3) fp32 -> out (32,1,128,128) fp32
//
// Round 3:
//  prep_x: LDS-transpose version — coalesced float4 reads, contiguous writes.
//  conv_mfma: 2 output rows/block, 512 thr (8 waves: 2 wm x 4 wn), mt=8 nt=2,
//    fully-unrolled (tap,kc) loop so B(L2)/A(LDS) loads pipeline across taps.

typedef __attribute__((ext_vector_type(8))) short  short8;   // 8 x bf16
typedef __attribute__((ext_vector_type(4))) float  float4v;

#define CI 64
#define CO 128
#define HH 128
#define WW 128
#define HP 130
#define WP 130

#define XT_BYTES   ((size_t)32 * HP * WP * CI * 2)   // 69,222,400
#define WT_BYTES   ((size_t)9 * CO * CI * 2)         // 147,456

__device__ __forceinline__ unsigned short f2bf(float f) {
    unsigned int u = __float_as_uint(f);
    u = (u + 0x7fffu + ((u >> 16) & 1u)) >> 16;   // RNE
    return (unsigned short)u;
}

// ---------------- prep kernels ----------------

// One block per (b, hp) padded row. Coalesced fp32 loads -> LDS transpose
// (bf16, ci-contiguous per pixel, 16B-slot swizzled by wp&7) -> one
// contiguous 16,640 B coalesced global write.
__global__ __launch_bounds__(256) void prep_x(
    const float* __restrict__ x, unsigned short* __restrict__ xt)
{
    __shared__ __align__(16) char buf[WP * CI * 2];   // 16,640 B
    const int hp  = blockIdx.x;          // 0..129
    const int b   = blockIdx.y;
    const int tid = threadIdx.x;
    unsigned short* dst = xt + ((size_t)b * HP + hp) * WP * CI;

    const int h = hp - 1;
    if (h < 0 || h >= HH) {              // padding row: all zeros
        float4v z = {0.f, 0.f, 0.f, 0.f};
        #pragma unroll
        for (int k = 0; k < 5; ++k) {
            int idx = k * 256 + tid;
            if (idx < WP * CI / 8) ((float4v*)dst)[idx] = z;
        }
        return;
    }

    // thread = (c2 = ci/2, wq): loads ci0,ci0+1 rows, 16 w each
    const int c2  = tid >> 3;
    const int wq  = tid & 7;
    const int ci0 = c2 * 2;
    const float* row0 = x + (((size_t)b * CI + ci0) * HH + h) * WW + wq * 16;
    const float* row1 = row0 + (size_t)HH * WW;
    #pragma unroll
    for (int j4 = 0; j4 < 4; ++j4) {
        float4v a0 = *(const float4v*)(row0 + j4 * 4);
        float4v a1 = *(const float4v*)(row1 + j4 * 4);
        #pragma unroll
        for (int e = 0; e < 4; ++e) {
            int wp   = wq * 16 + j4 * 4 + e + 1;           // 1..128
            int slot = (ci0 >> 3) ^ (wp & 7);
            unsigned int pack = (unsigned int)f2bf(a0[e])
                              | ((unsigned int)f2bf(a1[e]) << 16);
            *(unsigned int*)(buf + wp * 128 + slot * 16 + (ci0 & 7) * 2) = pack;
        }
    }
    if (tid < 16) {                      // zero pad pixels wp=0, wp=129
        float4v z = {0.f, 0.f, 0.f, 0.f};
        int p   = tid >> 3;
        int off = (tid & 7) * 16;
        *(float4v*)(buf + (p ? 129 : 0) * 128 + off) = z;
    }
    __syncthreads();
    #pragma unroll
    for (int k = 0; k < 5; ++k) {
        int idx = k * 256 + tid;
        if (idx < WP * CI / 8)
            ((float4v*)dst)[idx] = ((const float4v*)buf)[idx];
    }
}

__global__ __launch_bounds__(256) void prep_w(
    const float* __restrict__ Wsrc, unsigned short* __restrict__ wt)
{
    int idx = blockIdx.x * 256 + threadIdx.x;          // (tap, co, ci)
    if (idx >= 9 * CO * CI) return;
    int ci  = idx & 63;
    int t   = idx >> 6;
    int co  = t & 127;
    int tap = t >> 7;
    wt[idx] = f2bf(Wsrc[((size_t)co * CI + ci) * 9 + tap]);
}

// ---------------- main MFMA kernel ----------------

#define LDSA_BYTES (4 * WP * CI * 2)   // 66,560

__global__ __launch_bounds__(512, 2) void conv_mfma(
    const unsigned short* __restrict__ xt,
    const unsigned short* __restrict__ wt,
    float* __restrict__ out)
{
    __shared__ __align__(16) char  ldsA[LDSA_BYTES];
    __shared__ float scratch[4][2][128];

    const int bx   = blockIdx.x;       // 2 output rows per block
    const int b    = blockIdx.y;
    const int tid  = threadIdx.x;
    const int wid  = tid >> 6;
    const int lane = tid & 63;
    const int l15  = lane & 15;
    const int quad = lane >> 4;
    const int wm   = wid & 1;          // which output row of the pair
    const int wn   = wid >> 1;         // co quarter (32 co each)
    const int n0   = wn * 32;

    // ---- stage A: padded rows 2bx..2bx+3 = contiguous 66,560 B ----
    const char* src = (const char*)xt + ((size_t)b * HP + 2 * bx) * WP * (CI * 2);
    {
        const int wbase0 = wid * 1024;
        const int loff   = lane * 16;
        #pragma unroll
        for (int r = 0; r < 8; ++r) {
            int wbase = r * 8192 + wbase0;
            __builtin_amdgcn_global_load_lds(
                (const __attribute__((address_space(1))) void*)(src + wbase + loff),
                (__attribute__((address_space(3))) void*)(ldsA + wbase),
                16, 0, 0);
        }
        if (wid == 0) {                // 1,024 B tail
            __builtin_amdgcn_global_load_lds(
                (const __attribute__((address_space(1))) void*)(src + 65536 + loff),
                (__attribute__((address_space(3))) void*)(ldsA + 65536),
                16, 0, 0);
        }
    }
    __syncthreads();

    float4v acc[8][2];
    #pragma unroll
    for (int mt = 0; mt < 8; ++mt)
        #pragma unroll
        for (int nt = 0; nt < 2; ++nt)
            acc[mt][nt] = (float4v){0.f, 0.f, 0.f, 0.f};

    #pragma unroll
    for (int tap = 0; tap < 9; ++tap) {
        const int dh = tap / 3;                    // compile-time (unrolled)
        const int dw = tap % 3;
        const int key = (dw + l15) & 7;
        const int rowbase = (wm + dh) * WP + dw + l15;
        #pragma unroll
        for (int kc = 0; kc < 2; ++kc) {
            short8 bf[2];
            #pragma unroll
            for (int nt = 0; nt < 2; ++nt) {
                int co = n0 + nt * 16 + l15;
                bf[nt] = *(const short8*)(wt +
                          (((size_t)tap * CO + co) * CI + kc * 32 + quad * 8));
            }
            const int sp = ((kc * 4 + quad) ^ key) * 16;
            short8 af[8];
            #pragma unroll
            for (int mt = 0; mt < 8; ++mt)
                af[mt] = *(const short8*)(ldsA + (rowbase + mt * 16) * 128 + sp);
            #pragma unroll
            for (int mt = 0; mt < 8; ++mt)
                #pragma unroll
                for (int nt = 0; nt < 2; ++nt)
                    acc[mt][nt] = __builtin_amdgcn_mfma_f32_16x16x32_bf16(
                        af[mt], bf[nt], acc[mt][nt], 0, 0, 0);
        }
    }

    // ---- epilogue: min over co, *2 ----
    // lane holds D[m = mt*16 + quad*4 + reg (col in row wm)][n = n0+nt*16+l15]
    float pm[8][4];
    #pragma unroll
    for (int mt = 0; mt < 8; ++mt)
        #pragma unroll
        for (int reg = 0; reg < 4; ++reg)
            pm[mt][reg] = fminf(acc[mt][0][reg], acc[mt][1][reg]);
    #pragma unroll
    for (int mask = 1; mask <= 8; mask <<= 1)
        #pragma unroll
        for (int mt = 0; mt < 8; ++mt)
            #pragma unroll
            for (int reg = 0; reg < 4; ++reg)
                pm[mt][reg] = fminf(pm[mt][reg],
                                    __shfl_xor(pm[mt][reg], mask, 64));
    if (l15 == 0) {
        #pragma unroll
        for (int mt = 0; mt < 8; ++mt)
            #pragma unroll
            for (int reg = 0; reg < 4; ++reg)
                scratch[wn][wm][mt * 16 + quad * 4 + reg] = pm[mt][reg];
    }
    __syncthreads();
    if (tid < 256) {
        int r = tid >> 7, c = tid & 127;
        float v = fminf(fminf(scratch[0][r][c], scratch[1][r][c]),
                        fminf(scratch[2][r][c], scratch[3][r][c])) * 2.0f;
        out[((size_t)b * HH + 2 * bx + r) * WW + c] = v;
    }
}

// ---------------- fallback (round-1 direct conv) ----------------

#define COT 16
__global__ __launch_bounds__(256) void conv_min_fallback(
    const float* __restrict__ x, const float* __restrict__ Wt,
    float* __restrict__ out)
{
    const int b  = blockIdx.y;
    const int h  = blockIdx.x * 2 + (threadIdx.x >> 7);
    const int w  = threadIdx.x & 127;
    const bool r0 = h > 0, r2 = h < HH - 1, c0 = w > 0, c2 = w < WW - 1;
    const float* xb = x + (size_t)b * CI * HH * WW;
    float vmin = 3.4e38f;
    for (int cb = 0; cb < CO; cb += COT) {
        float acc[COT];
        #pragma unroll
        for (int u = 0; u < COT; ++u) acc[u] = 0.0f;
        #pragma unroll 1
        for (int ci = 0; ci < CI; ++ci) {
            const float* xp = xb + ((size_t)ci * HH + h) * WW + w;
            float xv[9];
            xv[0] = (r0 && c0) ? xp[-WW - 1] : 0.0f;
            xv[1] =  r0        ? xp[-WW    ] : 0.0f;
            xv[2] = (r0 && c2) ? xp[-WW + 1] : 0.0f;
            xv[3] =        c0  ? xp[-1     ] : 0.0f;
            xv[4] =              xp[0      ];
            xv[5] =        c2  ? xp[1      ] : 0.0f;
            xv[6] = (r2 && c0) ? xp[ WW - 1] : 0.0f;
            xv[7] =  r2        ? xp[ WW    ] : 0.0f;
            xv[8] = (r2 && c2) ? xp[ WW + 1] : 0.0f;
            #pragma unroll
            for (int u = 0; u < COT; ++u) {
                const float* wp = Wt + ((size_t)(cb + u) * CI + ci) * 9;
                acc[u] += wp[0]*xv[0] + wp[1]*xv[1] + wp[2]*xv[2]
                        + wp[3]*xv[3] + wp[4]*xv[4] + wp[5]*xv[5]
                        + wp[6]*xv[6] + wp[7]*xv[7] + wp[8]*xv[8];
            }
        }
        #pragma unroll
        for (int u = 0; u < COT; ++u) vmin = fminf(vmin, acc[u]);
    }
    out[((size_t)b * HH + h) * WW + w] = vmin * 2.0f;
}

// ---------------- launch ----------------

extern "C" void kernel_launch(void* const* d_in, const int* in_sizes, int n_in,
                              void* d_out, int out_size, void* d_ws, size_t ws_size,
                              hipStream_t stream) {
    const float* x  = (const float*)d_in[0];   // (32,64,128,128)
    const float* Ws = (const float*)d_in[1];   // (128,64,3,3)
    float* out = (float*)d_out;                // (32,1,128,128)

    if (ws_size < XT_BYTES + WT_BYTES) {
        dim3 grid(HH / 2, 32);
        conv_min_fallback<<<grid, 256, 0, stream>>>(x, Ws, out);
        return;
    }

    unsigned short* xt = (unsigned short*)d_ws;
    unsigned short* wt = (unsigned short*)((char*)d_ws + XT_BYTES);

    prep_x<<<dim3(HP, 32), 256, 0, stream>>>(x, xt);
    prep_w<<<(9 * CO * CI + 255) / 256, 256, 0, stream>>>(Ws, wt);
    conv_mfma<<<dim3(HH / 2, 32), 512, 0, stream>>>(xt, wt, out);
}

// Round 4
// 265.755 us; speedup vs baseline: 5.9129x; 1.1771x over previous
//
#include <hip/hip_runtime.h>

// out = min_co( conv2d(x, W, SAME) ) * 2
// x (32,64,128,128) fp32, W (128,64,3,3) fp32 -> out (32,1,128,128) fp32
//
// Round 4: single fused kernel. Each block (2 output rows):
//   stage: direct fp32 reads of 4 padded x rows (coalesced 512B segments),
//          in-register bf16 convert+pack, transposed swizzled LDS store.
//   GEMM:  M=2x128 pixels, N=128 co, K=9 taps x 64 ci, 16x16x32 bf16 MFMA,
//          B fragments register-double-buffered (prefetch hides L2 latency).
//   epilogue: min over co via shfl butterfly + LDS, *2, coalesced store.
// Only workspace: W_t[tap][co][ci] bf16 (147 KB) from tiny prep_w.

typedef __attribute__((ext_vector_type(8))) short  short8;   // 8 x bf16
typedef __attribute__((ext_vector_type(4))) float  float4v;

#define CI 64
#define CO 128
#define HH 128
#define WW 128
#define WP 130

#define WT_BYTES ((size_t)9 * CO * CI * 2)   // 147,456

__device__ __forceinline__ unsigned short f2bf(float f) {
    unsigned int u = __float_as_uint(f);
    u = (u + 0x7fffu + ((u >> 16) & 1u)) >> 16;   // RNE
    return (unsigned short)u;
}

// ---------------- prep_w: W (co,ci,3,3) fp32 -> wt[tap][co][ci] bf16 ------

__global__ __launch_bounds__(256) void prep_w(
    const float* __restrict__ Wsrc, unsigned short* __restrict__ wt)
{
    int idx = blockIdx.x * 256 + threadIdx.x;          // (tap, co, ci)
    if (idx >= 9 * CO * CI) return;
    int ci  = idx & 63;
    int t   = idx >> 6;
    int co  = t & 127;
    int tap = t >> 7;
    wt[idx] = f2bf(Wsrc[((size_t)co * CI + ci) * 9 + tap]);
}

// ---------------- fused conv + min ----------------

#define LDSA_BYTES (4 * WP * CI * 2)   // 66,560 : 4 padded rows, 128 B/pixel

__global__ __launch_bounds__(512, 4) void conv_fused(
    const float* __restrict__ x,
    const unsigned short* __restrict__ wt,
    float* __restrict__ out)
{
    __shared__ __align__(16) char  ldsA[LDSA_BYTES];
    __shared__ float scratch[4][2][128];

    const int bx   = blockIdx.x;       // output rows 2bx, 2bx+1
    const int b    = blockIdx.y;
    const int tid  = threadIdx.x;
    const int wid  = tid >> 6;
    const int lane = tid & 63;
    const int l15  = lane & 15;
    const int quad = lane >> 4;
    const int wm   = wid & 1;          // which output row of the pair
    const int wn   = wid >> 1;         // co quarter (32 co each)
    const int n0   = wn * 32;

    // ---- zero pad columns (wp = 0, 129) of all 4 LDS rows ----
    if (tid < 64) {
        int r    = tid >> 4;
        int wp   = ((tid >> 3) & 1) ? 129 : 0;
        int slot = tid & 7;
        float4v z = {0.f, 0.f, 0.f, 0.f};
        *(float4v*)(ldsA + ((size_t)(r * WP + wp) * 128) + slot * 16) = z;
    }
    // ---- zero out-of-bounds rows (edge blocks only; wave-uniform branch) ----
    if (bx == 0) {                      // LDS row 0 = x row -1
        float4v z = {0.f, 0.f, 0.f, 0.f};
        for (int i = tid; i < WP * CI * 2 / 16; i += 512)
            ((float4v*)ldsA)[i] = z;
    }
    if (bx == HH / 2 - 1) {             // LDS row 3 = x row 128
        float4v z = {0.f, 0.f, 0.f, 0.f};
        for (int i = tid; i < WP * CI * 2 / 16; i += 512)
            ((float4v*)(ldsA + 3 * WP * 128))[i] = z;
    }

    // ---- stage: fp32 -> bf16 transpose into LDS ----
    // task (r, cp, wq): ci pair (2cp, 2cp+1), w quad wq*4..wq*4+3, LDS row r.
    {
        const int wq  = tid & 31;          // 32 lanes -> 512 B contiguous / ci
        const int cph = tid >> 5;          // 0..15
        #pragma unroll
        for (int k = 0; k < 8; ++k) {
            const int r   = k >> 1;
            const int cp  = ((k & 1) << 4) + cph;   // 0..31
            const int ci0 = cp * 2;
            const int h   = 2 * bx - 1 + r;
            if (h >= 0 && h < HH) {
                const float* p0 = x + (((size_t)b * CI + ci0) * HH + h) * WW + wq * 4;
                float4v a0 = *(const float4v*)p0;
                float4v a1 = *(const float4v*)(p0 + (size_t)HH * WW);
                #pragma unroll
                for (int e = 0; e < 4; ++e) {
                    const int wp   = wq * 4 + e + 1;            // 1..128
                    const int slot = (ci0 >> 3) ^ (wp & 7);     // 16B-slot swizzle
                    unsigned int pack = (unsigned int)f2bf(a0[e])
                                      | ((unsigned int)f2bf(a1[e]) << 16);
                    *(unsigned int*)(ldsA + (size_t)(r * WP + wp) * 128
                                     + slot * 16 + (ci0 & 7) * 2) = pack;
                }
            }
        }
    }
    __syncthreads();

    // ---- K-loop: 9 taps x 2 kc, B register-double-buffered ----
    float4v acc[8][2];
    #pragma unroll
    for (int mt = 0; mt < 8; ++mt)
        #pragma unroll
        for (int nt = 0; nt < 2; ++nt)
            acc[mt][nt] = (float4v){0.f, 0.f, 0.f, 0.f};

    const unsigned short* wt_lane = wt + (size_t)(n0 + l15) * CI + quad * 8;

    short8 bcur[2], bnxt[2];
    bcur[0] = *(const short8*)(wt_lane);
    bcur[1] = *(const short8*)(wt_lane + 16 * CI);

    #pragma unroll
    for (int it = 0; it < 18; ++it) {
        const int tap = it >> 1;
        const int kc  = it & 1;
        const int dh  = tap / 3;
        const int dw  = tap % 3;

        if (it < 17) {                         // prefetch next B fragments
            const int tn   = it + 1;
            const size_t o = (size_t)(tn >> 1) * CO * CI + (tn & 1) * 32;
            bnxt[0] = *(const short8*)(wt_lane + o);
            bnxt[1] = *(const short8*)(wt_lane + o + 16 * CI);
        }

        const int key     = (dw + l15) & 7;
        const int rowbase = (wm + dh) * WP + dw + l15;
        const int sp      = ((kc * 4 + quad) ^ key) * 16;

        short8 af[8];
        #pragma unroll
        for (int mt = 0; mt < 8; ++mt)
            af[mt] = *(const short8*)(ldsA + (size_t)(rowbase + mt * 16) * 128 + sp);

        #pragma unroll
        for (int mt = 0; mt < 8; ++mt)
            #pragma unroll
            for (int nt = 0; nt < 2; ++nt)
                acc[mt][nt] = __builtin_amdgcn_mfma_f32_16x16x32_bf16(
                    af[mt], bcur[nt], acc[mt][nt], 0, 0, 0);

        bcur[0] = bnxt[0];
        bcur[1] = bnxt[1];
    }

    // ---- epilogue: min over co, *2 ----
    // lane holds D[m = mt*16 + quad*4 + reg (pixel in row wm)][n = n0+nt*16+l15]
    float pm[8][4];
    #pragma unroll
    for (int mt = 0; mt < 8; ++mt)
        #pragma unroll
        for (int reg = 0; reg < 4; ++reg)
            pm[mt][reg] = fminf(acc[mt][0][reg], acc[mt][1][reg]);
    #pragma unroll
    for (int mask = 1; mask <= 8; mask <<= 1)
        #pragma unroll
        for (int mt = 0; mt < 8; ++mt)
            #pragma unroll
            for (int reg = 0; reg < 4; ++reg)
                pm[mt][reg] = fminf(pm[mt][reg],
                                    __shfl_xor(pm[mt][reg], mask, 64));
    if (l15 == 0) {
        #pragma unroll
        for (int mt = 0; mt < 8; ++mt)
            #pragma unroll
            for (int reg = 0; reg < 4; ++reg)
                scratch[wn][wm][mt * 16 + quad * 4 + reg] = pm[mt][reg];
    }
    __syncthreads();
    if (tid < 256) {
        int r = tid >> 7, c = tid & 127;
        float v = fminf(fminf(scratch[0][r][c], scratch[1][r][c]),
                        fminf(scratch[2][r][c], scratch[3][r][c])) * 2.0f;
        out[((size_t)b * HH + 2 * bx + r) * WW + c] = v;
    }
}

// ---------------- fallback (round-1 direct conv) ----------------

#define COT 16
__global__ __launch_bounds__(256) void conv_min_fallback(
    const float* __restrict__ x, const float* __restrict__ Wt,
    float* __restrict__ out)
{
    const int b  = blockIdx.y;
    const int h  = blockIdx.x * 2 + (threadIdx.x >> 7);
    const int w  = threadIdx.x & 127;
    const bool r0 = h > 0, r2 = h < HH - 1, c0 = w > 0, c2 = w < WW - 1;
    const float* xb = x + (size_t)b * CI * HH * WW;
    float vmin = 3.4e38f;
    for (int cb = 0; cb < CO; cb += COT) {
        float acc[COT];
        #pragma unroll
        for (int u = 0; u < COT; ++u) acc[u] = 0.0f;
        #pragma unroll 1
        for (int ci = 0; ci < CI; ++ci) {
            const float* xp = xb + ((size_t)ci * HH + h) * WW + w;
            float xv[9];
            xv[0] = (r0 && c0) ? xp[-WW - 1] : 0.0f;
            xv[1] =  r0        ? xp[-WW    ] : 0.0f;
            xv[2] = (r0 && c2) ? xp[-WW + 1] : 0.0f;
            xv[3] =        c0  ? xp[-1     ] : 0.0f;
            xv[4] =              xp[0      ];
            xv[5] =        c2  ? xp[1      ] : 0.0f;
            xv[6] = (r2 && c0) ? xp[ WW - 1] : 0.0f;
            xv[7] =  r2        ? xp[ WW    ] : 0.0f;
            xv[8] = (r2 && c2) ? xp[ WW + 1] : 0.0f;
            #pragma unroll
            for (int u = 0; u < COT; ++u) {
                const float* wp = Wt + ((size_t)(cb + u) * CI + ci) * 9;
                acc[u] += wp[0]*xv[0] + wp[1]*xv[1] + wp[2]*xv[2]
                        + wp[3]*xv[3] + wp[4]*xv[4] + wp[5]*xv[5]
                        + wp[6]*xv[6] + wp[7]*xv[7] + wp[8]*xv[8];
            }
        }
        #pragma unroll
        for (int u = 0; u < COT; ++u) vmin = fminf(vmin, acc[u]);
    }
    out[((size_t)b * HH + h) * WW + w] = vmin * 2.0f;
}

// ---------------- launch ----------------

extern "C" void kernel_launch(void* const* d_in, const int* in_sizes, int n_in,
                              void* d_out, int out_size, void* d_ws, size_t ws_size,
                              hipStream_t stream) {
    const float* x  = (const float*)d_in[0];   // (32,64,128,128)
    const float* Ws = (const float*)d_in[1];   // (128,64,3,3)
    float* out = (float*)d_out;                // (32,1,128,128)

    if (ws_size < WT_BYTES) {
        dim3 grid(HH / 2, 32);
        conv_min_fallback<<<grid, 256, 0, stream>>>(x, Ws, out);
        return;
    }

    unsigned short* wt = (unsigned short*)d_ws;

    prep_w<<<(9 * CO * CI + 255) / 256, 256, 0, stream>>>(Ws, wt);
    conv_fused<<<dim3(HH / 2, 32), 512, 0, stream>>>(x, wt, out);
}